// Round 5
// baseline (542.155 us; speedup 1.0000x reference)
//
#include <hip/hip_runtime.h>
#include <math.h>

#define HN 56
#define WN 56
#define LN 3136
#define BN 4
#define DIN 192
#define NST 16
#define KD 4
#define DTR 6
#define CPROJ 38
#define CL 56
#define NC 56
#define DMODEL 96

__device__ __forceinline__ float silu_f(float x){ return x / (1.0f + __expf(-x)); }
__device__ __forceinline__ float softplus_f(float x){ return (x > 20.0f) ? x : log1pf(__expf(x)); }

// sequence position s of direction k -> row-major spatial location
__device__ __forceinline__ int seq_to_loc(int k, int s){
  int ss = (k & 2) ? (LN - 1 - s) : s;
  if (k & 1) { int h = ss % HN; int w = ss / HN; return h * WN + w; }
  return ss;
}

// ---------------- K1: in_proj GEMM (12544 x 384, K=96) ----------------
__global__ __launch_bounds__(256) void k1_inproj(const float* __restrict__ x,
    const float* __restrict__ w, float* __restrict__ xi, float* __restrict__ sz){
  __shared__ float sx[32*100];   // padded stride 100 to avoid bank conflicts
  __shared__ float sw[96*100];
  int t = threadIdx.x;
  int m0 = blockIdx.x * 32;          // row tile
  int g  = blockIdx.y;               // col group: cols g*96 .. g*96+95
  const float* xb = x + (size_t)m0 * 96;
  const float* wb = w + (size_t)g * 96 * 96;
  for (int i = t; i < 32*96; i += 256) sx[(i/96)*100 + (i%96)] = xb[i];
  for (int i = t; i < 96*96; i += 256) sw[(i/96)*100 + (i%96)] = wb[i];
  __syncthreads();
  int li0 = (t & 7) * 4;
  int c0  = (t >> 3) * 3;
  float acc[4][3];
  #pragma unroll
  for (int j=0;j<4;j++){ acc[j][0]=0.f; acc[j][1]=0.f; acc[j][2]=0.f; }
  for (int i = 0; i < 96; i += 4) {
    float4 xv[4], wv[3];
    #pragma unroll
    for (int j=0;j<4;j++) xv[j] = *(const float4*)&sx[(li0+j)*100 + i];
    #pragma unroll
    for (int m=0;m<3;m++) wv[m] = *(const float4*)&sw[(c0+m)*100 + i];
    #pragma unroll
    for (int j=0;j<4;j++){
      #pragma unroll
      for (int m=0;m<3;m++){
        acc[j][m] += xv[j].x*wv[m].x + xv[j].y*wv[m].y + xv[j].z*wv[m].z + xv[j].w*wv[m].w;
      }
    }
  }
  #pragma unroll
  for (int j=0;j<4;j++){
    int row = m0 + li0 + j;
    #pragma unroll
    for (int m=0;m<3;m++){
      int o = g*96 + c0 + m;
      float v = acc[j][m];
      if (o < DIN) xi[(size_t)row*DIN + o] = v;
      else         sz[(size_t)row*DIN + (o - DIN)] = silu_f(v);
    }
  }
}

// ---------------- K2: depthwise conv 3x3 + silu; also y_init = xc * sum_k D ----------------
__global__ __launch_bounds__(256) void k2_conv(const float* __restrict__ xi,
    const float* __restrict__ cw, const float* __restrict__ cb,
    const float* __restrict__ Ds,
    float* __restrict__ xc, float* __restrict__ ysum){
  int t = blockIdx.x * 256 + threadIdx.x;
  const int total = BN * LN * (DIN/4);
  if (t >= total) return;
  int c4 = t % (DIN/4); int m = t / (DIN/4);
  int c = c4 * 4;
  int b = m / LN; int loc = m % LN;
  int h = loc / WN; int w = loc % WN;
  float acc[4];
  #pragma unroll
  for (int j=0;j<4;j++) acc[j] = cb[c+j];
  float wgt[4][9];
  #pragma unroll
  for (int j=0;j<4;j++)
    #pragma unroll
    for (int q=0;q<9;q++) wgt[j][q] = cw[(c+j)*9 + q];
  for (int dh=-1; dh<=1; dh++){
    int hh = h + dh; if (hh < 0 || hh >= HN) continue;
    for (int dw=-1; dw<=1; dw++){
      int ww = w + dw; if (ww < 0 || ww >= WN) continue;
      const float4 xv = *(const float4*)&xi[((size_t)(b*LN + hh*WN + ww))*DIN + c];
      int q = (dh+1)*3 + (dw+1);
      acc[0] += xv.x * wgt[0][q];
      acc[1] += xv.y * wgt[1][q];
      acc[2] += xv.z * wgt[2][q];
      acc[3] += xv.w * wgt[3][q];
    }
  }
  float4 xcv, yv;
  #pragma unroll
  for (int j=0;j<4;j++){
    float v = silu_f(acc[j]);
    float sd = Ds[c+j] + Ds[DIN + c+j] + Ds[2*DIN + c+j] + Ds[3*DIN + c+j];
    ((float*)&xcv)[j] = v;
    ((float*)&yv)[j]  = v * sd;
  }
  *(float4*)&xc[(size_t)m*DIN + c]   = xcv;
  *(float4*)&ysum[(size_t)m*DIN + c] = yv;
}

// ---------------- K3: x_proj (38x192) + dt_proj (192x6) + softplus ----------------
__global__ __launch_bounds__(256) void k3_proj(const float* __restrict__ xc,
    const float* __restrict__ xpw,   // (4,38,192)
    const float* __restrict__ dtw,   // (4,192,6)
    const float* __restrict__ dtb,   // (4,192)
    float* __restrict__ delta, float* __restrict__ Bsp, float* __restrict__ Csp){
  __shared__ float sx[16*192];
  __shared__ float sp[16*40];
  int t = threadIdx.x;
  int loc0 = blockIdx.x * 16;
  int b = blockIdx.y;
  int k = blockIdx.z;
  const float* xb = xc + ((size_t)b*LN + loc0)*DIN;
  for (int i = t; i < 16*192; i += 256) sx[i] = xb[i];
  __syncthreads();
  const float* wk = xpw + (size_t)k*CPROJ*DIN;
  size_t kbL = ((size_t)(k*BN + b))*LN;
  for (int o = t; o < 16*CPROJ; o += 256){
    int li = o / CPROJ; int cc = o % CPROJ;
    const float* wr = wk + (size_t)cc*DIN;
    const float* xr = sx + li*192;
    float a = 0.f;
    for (int i = 0; i < 192; i += 4){
      float4 xv = *(const float4*)&xr[i];
      float4 wv = *(const float4*)&wr[i];
      a += xv.x*wv.x + xv.y*wv.y + xv.z*wv.z + xv.w*wv.w;
    }
    sp[li*40 + cc] = a;
    int loc = loc0 + li;
    if (cc >= DTR){
      if (cc < DTR + NST) Bsp[(kbL + loc)*NST + (cc - DTR)] = a;
      else                Csp[(kbL + loc)*NST + (cc - DTR - NST)] = a;
    }
  }
  __syncthreads();
  const float* dtwk = dtw + (size_t)k*DIN*DTR;
  const float* dtbk = dtb + (size_t)k*DIN;
  for (int o = t; o < 16*DIN; o += 256){
    int li = o / DIN; int d = o % DIN;
    float a = dtbk[d];
    const float* wr = dtwk + d*DTR;
    const float* pr = sp + li*40;
    #pragma unroll
    for (int r=0;r<DTR;r++) a += pr[r]*wr[r];
    delta[(kbL + loc0 + li)*DIN + d] = softplus_f(a);
  }
}

// ---------------- K4: scan pass 1 — per-chunk summaries (P = prod dA, Hc = local end state) ----------------
__global__ __launch_bounds__(192) void k4_pass1(const float* __restrict__ delta,
    const float* __restrict__ xc, const float* __restrict__ Bsp,
    const float* __restrict__ A_logs,
    float* __restrict__ Pc, float* __restrict__ Hc){
  __shared__ float sB[CL*NST];
  int d = threadIdx.x;
  int c = blockIdx.x, b = blockIdx.y, k = blockIdx.z;
  int kb = k*BN + b;
  for (int i = d; i < CL*NST; i += 192){
    int sl = i / NST, n = i % NST;
    int loc = seq_to_loc(k, c*CL + sl);
    sB[i] = Bsp[((size_t)kb*LN + loc)*NST + n];
  }
  float A[NST];
  const float* ap = A_logs + ((size_t)k*DIN + d)*NST;
  #pragma unroll
  for (int n=0;n<NST;n++) A[n] = -__expf(ap[n]);
  __syncthreads();
  float h[NST], P[NST];
  #pragma unroll
  for (int n=0;n<NST;n++){ h[n]=0.f; P[n]=1.f; }
  const float* dp = delta + (size_t)kb*LN*DIN + d;
  const float* up = xc + (size_t)b*LN*DIN + d;
  for (int sl = 0; sl < CL; sl++){
    int loc = seq_to_loc(k, c*CL + sl);
    float dl = dp[(size_t)loc*DIN];
    float uu = up[(size_t)loc*DIN];
    float du = dl * uu;
    const float* bb = sB + sl*NST;
    #pragma unroll
    for (int n=0;n<NST;n++){
      float e = __expf(dl * A[n]);
      h[n] = e*h[n] + du*bb[n];
      P[n] *= e;
    }
  }
  size_t base = (((size_t)kb*NC + c)*DIN + d)*NST;
  #pragma unroll
  for (int n=0;n<NST;n++){ Pc[base+n] = P[n]; Hc[base+n] = h[n]; }
}

// ---------------- K5: scan pass 2 — compose chunk summaries; writes h_in over Pc (alias) ----------------
__global__ __launch_bounds__(256) void k5_pass2(float* __restrict__ Pc,
    const float* __restrict__ Hc){
  int idx = blockIdx.x*256 + threadIdx.x;
  if (idx >= KD*BN*DIN*NST) return;
  int kb = idx / (DIN*NST);
  int dn = idx % (DIN*NST);
  size_t base = (size_t)kb*NC*DIN*NST + dn;
  float h = 0.f;
  for (int c = 0; c < NC; c++){
    size_t o = base + (size_t)c*DIN*NST;
    float p = Pc[o];
    float hv = Hc[o];
    Pc[o] = h;          // store h_in for chunk c
    h = p*h + hv;
  }
}

// ---------------- K6: scan pass 3 — recompute with correct h_in, emit y ----------------
__global__ __launch_bounds__(192) void k6_pass3(const float* __restrict__ delta,
    const float* __restrict__ xc, const float* __restrict__ Bsp,
    const float* __restrict__ Csp, const float* __restrict__ A_logs,
    const float* __restrict__ hin, float* __restrict__ ysum){
  __shared__ float sB[CL*NST];
  __shared__ float sC[CL*NST];
  int d = threadIdx.x;
  int c = blockIdx.x, b = blockIdx.y, k = blockIdx.z;
  int kb = k*BN + b;
  for (int i = d; i < CL*NST; i += 192){
    int sl = i / NST, n = i % NST;
    int loc = seq_to_loc(k, c*CL + sl);
    sB[i] = Bsp[((size_t)kb*LN + loc)*NST + n];
    sC[i] = Csp[((size_t)kb*LN + loc)*NST + n];
  }
  float A[NST];
  const float* ap = A_logs + ((size_t)k*DIN + d)*NST;
  #pragma unroll
  for (int n=0;n<NST;n++) A[n] = -__expf(ap[n]);
  float h[NST];
  size_t hb = (((size_t)kb*NC + c)*DIN + d)*NST;
  #pragma unroll
  for (int n=0;n<NST;n++) h[n] = hin[hb+n];
  __syncthreads();
  const float* dp = delta + (size_t)kb*LN*DIN + d;
  const float* up = xc + (size_t)b*LN*DIN + d;
  float* yp = ysum + (size_t)b*LN*DIN + d;
  for (int sl = 0; sl < CL; sl++){
    int loc = seq_to_loc(k, c*CL + sl);
    float dl = dp[(size_t)loc*DIN];
    float uu = up[(size_t)loc*DIN];
    float du = dl * uu;
    const float* bb = sB + sl*NST;
    const float* cc2 = sC + sl*NST;
    float y = 0.f;
    #pragma unroll
    for (int n=0;n<NST;n++){
      float e = __expf(dl * A[n]);
      h[n] = e*h[n] + du*bb[n];
      y += h[n]*cc2[n];
    }
    atomicAdd(&yp[(size_t)loc*DIN], y);
  }
}

// ---------------- K7: LayerNorm + gate(silu z) + out_proj (96x192) ----------------
__global__ __launch_bounds__(256) void k7_out(const float* __restrict__ ysum,
    const float* __restrict__ sz, const float* __restrict__ gamma,
    const float* __restrict__ beta, const float* __restrict__ ow,
    float* __restrict__ out){
  __shared__ float sg[8*192];
  int t = threadIdx.x;
  int m0 = blockIdx.x * 8;
  int li = t >> 5;
  int j  = t & 31;
  int m = m0 + li;
  const float* yr = ysum + (size_t)m*DIN;
  float vals[6];
  float s1 = 0.f, s2 = 0.f;
  #pragma unroll
  for (int q=0;q<6;q++){
    float v = yr[j + 32*q];
    vals[q] = v; s1 += v; s2 += v*v;
  }
  #pragma unroll
  for (int off=16; off>=1; off>>=1){
    s1 += __shfl_xor(s1, off);
    s2 += __shfl_xor(s2, off);
  }
  float mu  = s1 * (1.0f/192.0f);
  float var = s2 * (1.0f/192.0f) - mu*mu;
  float rstd = rsqrtf(var + 1e-5f);
  const float* zr = sz + (size_t)m*DIN;
  #pragma unroll
  for (int q=0;q<6;q++){
    int dd = j + 32*q;
    float v = (vals[q]-mu)*rstd*gamma[dd] + beta[dd];
    sg[li*192 + dd] = v * zr[dd];
  }
  __syncthreads();
  for (int o = t; o < 8*DMODEL; o += 256){
    int lo = o / DMODEL; int cc = o % DMODEL;
    const float* gr = sg + lo*192;
    const float* wr = ow + (size_t)cc*DIN;
    float a = 0.f;
    for (int i=0;i<192;i+=4){
      float4 gv = *(const float4*)&gr[i];
      float4 wv = *(const float4*)&wr[i];
      a += gv.x*wv.x + gv.y*wv.y + gv.z*wv.z + gv.w*wv.w;
    }
    out[(size_t)(m0+lo)*DMODEL + cc] = a;
  }
}

extern "C" void kernel_launch(void* const* d_in, const int* in_sizes, int n_in,
                              void* d_out, int out_size, void* d_ws, size_t ws_size,
                              hipStream_t stream){
  (void)in_sizes; (void)n_in; (void)out_size; (void)ws_size;
  const float* x    = (const float*)d_in[0];
  const float* ipw  = (const float*)d_in[1];
  const float* cw   = (const float*)d_in[2];
  const float* cb   = (const float*)d_in[3];
  const float* xpw  = (const float*)d_in[4];
  const float* dtw  = (const float*)d_in[5];
  const float* dtb  = (const float*)d_in[6];
  const float* alog = (const float*)d_in[7];
  const float* Ds   = (const float*)d_in[8];
  const float* gam  = (const float*)d_in[9];
  const float* bet  = (const float*)d_in[10];
  const float* ow   = (const float*)d_in[11];
  float* out = (float*)d_out;

  float* ws = (float*)d_ws;
  const size_t BLD  = (size_t)BN*LN*DIN;          // 2,408,448
  const size_t KBLN = (size_t)KD*BN*LN*NST;       //   802,816
  const size_t SUMN = (size_t)KD*BN*NC*DIN*NST;   // 2,752,512

  float* xc    = ws;
  float* sz    = ws + BLD;
  float* ysum  = ws + 2*BLD;
  float* delta = ws + 3*BLD;        // 4*BLD
  float* xi    = delta;             // alias: xi dead once K2 done, K3 overwrites with delta
  float* Bsp   = ws + 7*BLD;
  float* Csp   = Bsp + KBLN;
  float* Pc    = Csp + KBLN;        // pass2 overwrites Pc with h_in (per-thread read-then-write)
  float* Hc    = Pc + SUMN;

  k1_inproj<<<dim3(392,4), 256, 0, stream>>>(x, ipw, xi, sz);
  k2_conv<<<2352, 256, 0, stream>>>(xi, cw, cb, Ds, xc, ysum);
  k3_proj<<<dim3(196,4,4), 256, 0, stream>>>(xc, xpw, dtw, dtb, delta, Bsp, Csp);
  k4_pass1<<<dim3(NC,4,4), 192, 0, stream>>>(delta, xc, Bsp, alog, Pc, Hc);
  k5_pass2<<<192, 256, 0, stream>>>(Pc, Hc);
  k6_pass3<<<dim3(NC,4,4), 192, 0, stream>>>(delta, xc, Bsp, Csp, alog, Pc, ysum);
  k7_out<<<1568, 256, 0, stream>>>(ysum, sz, gam, bet, ow, out);
}

// Round 9
// 430.934 us; speedup vs baseline: 1.2581x; 1.2581x over previous
//
#include <hip/hip_runtime.h>
#include <math.h>

#define HN 56
#define WN 56
#define LN 3136
#define BN 4
#define DIN 192
#define NST 16
#define KD 4
#define DTR 6
#define CPROJ 38
#define CL 56
#define NC 56
#define DMODEL 96

__device__ __forceinline__ float silu_f(float x){ return x / (1.0f + __expf(-x)); }
__device__ __forceinline__ float softplus_f(float x){ return (x > 20.0f) ? x : log1pf(__expf(x)); }

// sequence position s of direction k -> row-major spatial location
__device__ __forceinline__ int seq_to_loc(int k, int s){
  int ss = (k & 2) ? (LN - 1 - s) : s;
  if (k & 1) { int h = ss % HN; int w = ss / HN; return h * WN + w; }
  return ss;
}

// ---------------- K1: in_proj GEMM (12544 x 384, K=96) ----------------
__global__ __launch_bounds__(256) void k1_inproj(const float* __restrict__ x,
    const float* __restrict__ w, float* __restrict__ xi, float* __restrict__ sz){
  __shared__ float sx[32*100];   // padded stride 100 to avoid bank conflicts
  __shared__ float sw[96*100];
  int t = threadIdx.x;
  int m0 = blockIdx.x * 32;          // row tile
  int g  = blockIdx.y;               // col group: cols g*96 .. g*96+95
  const float* xb = x + (size_t)m0 * 96;
  const float* wb = w + (size_t)g * 96 * 96;
  for (int i = t; i < 32*96; i += 256) sx[(i/96)*100 + (i%96)] = xb[i];
  for (int i = t; i < 96*96; i += 256) sw[(i/96)*100 + (i%96)] = wb[i];
  __syncthreads();
  int li0 = (t & 7) * 4;
  int c0  = (t >> 3) * 3;
  float acc[4][3];
  #pragma unroll
  for (int j=0;j<4;j++){ acc[j][0]=0.f; acc[j][1]=0.f; acc[j][2]=0.f; }
  for (int i = 0; i < 96; i += 4) {
    float4 xv[4], wv[3];
    #pragma unroll
    for (int j=0;j<4;j++) xv[j] = *(const float4*)&sx[(li0+j)*100 + i];
    #pragma unroll
    for (int m=0;m<3;m++) wv[m] = *(const float4*)&sw[(c0+m)*100 + i];
    #pragma unroll
    for (int j=0;j<4;j++){
      #pragma unroll
      for (int m=0;m<3;m++){
        acc[j][m] += xv[j].x*wv[m].x + xv[j].y*wv[m].y + xv[j].z*wv[m].z + xv[j].w*wv[m].w;
      }
    }
  }
  #pragma unroll
  for (int j=0;j<4;j++){
    int row = m0 + li0 + j;
    #pragma unroll
    for (int m=0;m<3;m++){
      int o = g*96 + c0 + m;
      float v = acc[j][m];
      if (o < DIN) xi[(size_t)row*DIN + o] = v;
      else         sz[(size_t)row*DIN + (o - DIN)] = silu_f(v);
    }
  }
}

// ---------------- K2: depthwise conv 3x3 + silu; also y_init = xc * sum_k D ----------------
__global__ __launch_bounds__(256) void k2_conv(const float* __restrict__ xi,
    const float* __restrict__ cw, const float* __restrict__ cb,
    const float* __restrict__ Ds,
    float* __restrict__ xc, float* __restrict__ ysum){
  int t = blockIdx.x * 256 + threadIdx.x;
  const int total = BN * LN * (DIN/4);
  if (t >= total) return;
  int c4 = t % (DIN/4); int m = t / (DIN/4);
  int c = c4 * 4;
  int b = m / LN; int loc = m % LN;
  int h = loc / WN; int w = loc % WN;
  float acc[4];
  #pragma unroll
  for (int j=0;j<4;j++) acc[j] = cb[c+j];
  float wgt[4][9];
  #pragma unroll
  for (int j=0;j<4;j++)
    #pragma unroll
    for (int q=0;q<9;q++) wgt[j][q] = cw[(c+j)*9 + q];
  for (int dh=-1; dh<=1; dh++){
    int hh = h + dh; if (hh < 0 || hh >= HN) continue;
    for (int dw=-1; dw<=1; dw++){
      int ww = w + dw; if (ww < 0 || ww >= WN) continue;
      const float4 xv = *(const float4*)&xi[((size_t)(b*LN + hh*WN + ww))*DIN + c];
      int q = (dh+1)*3 + (dw+1);
      acc[0] += xv.x * wgt[0][q];
      acc[1] += xv.y * wgt[1][q];
      acc[2] += xv.z * wgt[2][q];
      acc[3] += xv.w * wgt[3][q];
    }
  }
  float4 xcv, yv;
  #pragma unroll
  for (int j=0;j<4;j++){
    float v = silu_f(acc[j]);
    float sd = Ds[c+j] + Ds[DIN + c+j] + Ds[2*DIN + c+j] + Ds[3*DIN + c+j];
    ((float*)&xcv)[j] = v;
    ((float*)&yv)[j]  = v * sd;
  }
  *(float4*)&xc[(size_t)m*DIN + c]   = xcv;
  *(float4*)&ysum[(size_t)m*DIN + c] = yv;
}

// ---------------- K3: x_proj (38x192) + dt_proj (192x6) + softplus ----------------
// Register-tiled GEMM: 64-loc tile, W staged once in LDS (stride 196, bank-spread),
// X streamed in 64x48 chunks (stride 52), thread = (rowg,colg) -> 2x5 acc tile.
__global__ __launch_bounds__(256) void k3_proj(const float* __restrict__ xc,
    const float* __restrict__ xpw,   // (4,38,192)
    const float* __restrict__ dtw,   // (4,192,6)
    const float* __restrict__ dtb,   // (4,192)
    float* __restrict__ delta, float* __restrict__ Bsp, float* __restrict__ Csp){
  __shared__ float sw[40*196];   // 38 real rows + 2 zero rows, padded stride
  __shared__ float sx[64*52];    // 64 rows x 48 K-chunk, padded stride
  __shared__ float sdt[DIN*DTR];
  __shared__ float sp[64*8];
  int t = threadIdx.x;
  int loc0 = blockIdx.x * 64;
  int b = blockIdx.y;
  int k = blockIdx.z;
  int kb = k*BN + b;
  const float* wk = xpw + (size_t)k*CPROJ*DIN;
  // stage W (40x48 float4s)
  for (int f = t; f < 40*48; f += 256){
    int row = f / 48, cf = f % 48;
    float4 v;
    if (row < CPROJ) v = *(const float4*)&wk[(size_t)row*DIN + cf*4];
    else             v = make_float4(0.f,0.f,0.f,0.f);
    *(float4*)&sw[row*196 + cf*4] = v;
  }
  // stage dtw
  const float* dtwk = dtw + (size_t)k*DIN*DTR;
  for (int f = t; f < DIN*DTR; f += 256) sdt[f] = dtwk[f];
  int rowg = t >> 3;   // 0..31
  int colg = t & 7;    // 0..7
  float acc[2][5];
  #pragma unroll
  for (int r=0;r<2;r++)
    #pragma unroll
    for (int c=0;c<5;c++) acc[r][c] = 0.f;
  const float* xb = xc + ((size_t)b*LN + loc0)*DIN;
  for (int ck = 0; ck < 4; ck++){
    __syncthreads();
    #pragma unroll
    for (int j = 0; j < 3; j++){
      int f = t + j*256;             // 768 float4s = 64 rows x 12
      int row = f / 12, cf = f % 12;
      *(float4*)&sx[row*52 + cf*4] = *(const float4*)&xb[(size_t)row*DIN + ck*48 + cf*4];
    }
    __syncthreads();
    #pragma unroll
    for (int q = 0; q < 12; q++){
      float4 xv0 = *(const float4*)&sx[(rowg*2+0)*52 + q*4];
      float4 xv1 = *(const float4*)&sx[(rowg*2+1)*52 + q*4];
      #pragma unroll
      for (int c=0;c<5;c++){
        float4 wv = *(const float4*)&sw[(colg*5+c)*196 + ck*48 + q*4];
        acc[0][c] += xv0.x*wv.x + xv0.y*wv.y + xv0.z*wv.z + xv0.w*wv.w;
        acc[1][c] += xv1.x*wv.x + xv1.y*wv.y + xv1.z*wv.z + xv1.w*wv.w;
      }
    }
  }
  // scatter results: cols 0..5 -> sp (LDS), 6..21 -> B, 22..37 -> C
  size_t kbL = (size_t)kb*LN;
  #pragma unroll
  for (int r=0;r<2;r++){
    int lrow = rowg*2 + r;
    int loc  = loc0 + lrow;
    #pragma unroll
    for (int c=0;c<5;c++){
      int col = colg*5 + c;
      float v = acc[r][c];
      if (col < DTR)               sp[lrow*8 + col] = v;
      else if (col < DTR+NST)      Bsp[(kbL+loc)*NST + (col-DTR)] = v;
      else if (col < CPROJ)        Csp[(kbL+loc)*NST + (col-DTR-NST)] = v;
    }
  }
  __syncthreads();
  // epilogue: delta = softplus(dtb + sp . dtw^T)
  const float* dtbk = dtb + (size_t)k*DIN;
  for (int o = t; o < 64*DIN; o += 256){
    int li = o / DIN, d = o % DIN;
    float a = dtbk[d];
    const float* pr = &sp[li*8];
    #pragma unroll
    for (int r=0;r<DTR;r++) a += pr[r]*sdt[d*DTR+r];
    delta[(kbL + loc0 + li)*DIN + d] = softplus_f(a);
  }
}

// ---------------- K4: scan pass 1 — per-chunk summaries (P = prod dA, Hc = local end state) ----------------
__global__ __launch_bounds__(192) void k4_pass1(const float* __restrict__ delta,
    const float* __restrict__ xc, const float* __restrict__ Bsp,
    const float* __restrict__ A_logs,
    float* __restrict__ Pc, float* __restrict__ Hc){
  __shared__ float sB[CL*NST];
  int d = threadIdx.x;
  int c = blockIdx.x, b = blockIdx.y, k = blockIdx.z;
  int kb = k*BN + b;
  for (int i = d; i < CL*NST; i += 192){
    int sl = i / NST, n = i % NST;
    int loc = seq_to_loc(k, c*CL + sl);
    sB[i] = Bsp[((size_t)kb*LN + loc)*NST + n];
  }
  float A[NST];
  const float* ap = A_logs + ((size_t)k*DIN + d)*NST;
  #pragma unroll
  for (int n=0;n<NST;n++) A[n] = -__expf(ap[n]);
  __syncthreads();
  float h[NST], P[NST];
  #pragma unroll
  for (int n=0;n<NST;n++){ h[n]=0.f; P[n]=1.f; }
  const float* dp = delta + (size_t)kb*LN*DIN + d;
  const float* up = xc + (size_t)b*LN*DIN + d;
  for (int sl = 0; sl < CL; sl++){
    int loc = seq_to_loc(k, c*CL + sl);
    float dl = dp[(size_t)loc*DIN];
    float uu = up[(size_t)loc*DIN];
    float du = dl * uu;
    const float* bb = sB + sl*NST;
    #pragma unroll
    for (int n=0;n<NST;n++){
      float e = __expf(dl * A[n]);
      h[n] = e*h[n] + du*bb[n];
      P[n] *= e;
    }
  }
  size_t base = (((size_t)kb*NC + c)*DIN + d)*NST;
  #pragma unroll
  for (int n=0;n<NST;n++){ Pc[base+n] = P[n]; Hc[base+n] = h[n]; }
}

// ---------------- K5: scan pass 2 — compose chunk summaries; writes h_in over Pc (alias) ----------------
__global__ __launch_bounds__(256) void k5_pass2(float* __restrict__ Pc,
    const float* __restrict__ Hc){
  int idx = blockIdx.x*256 + threadIdx.x;
  if (idx >= KD*BN*DIN*NST) return;
  int kb = idx / (DIN*NST);
  int dn = idx % (DIN*NST);
  size_t base = (size_t)kb*NC*DIN*NST + dn;
  float h = 0.f;
  for (int c = 0; c < NC; c++){
    size_t o = base + (size_t)c*DIN*NST;
    float p = Pc[o];
    float hv = Hc[o];
    Pc[o] = h;          // store h_in for chunk c
    h = p*h + hv;
  }
}

// ---------------- K6: scan pass 3 — recompute with correct h_in, emit y ----------------
__global__ __launch_bounds__(192) void k6_pass3(const float* __restrict__ delta,
    const float* __restrict__ xc, const float* __restrict__ Bsp,
    const float* __restrict__ Csp, const float* __restrict__ A_logs,
    const float* __restrict__ hin, float* __restrict__ ysum){
  __shared__ float sB[CL*NST];
  __shared__ float sC[CL*NST];
  int d = threadIdx.x;
  int c = blockIdx.x, b = blockIdx.y, k = blockIdx.z;
  int kb = k*BN + b;
  for (int i = d; i < CL*NST; i += 192){
    int sl = i / NST, n = i % NST;
    int loc = seq_to_loc(k, c*CL + sl);
    sB[i] = Bsp[((size_t)kb*LN + loc)*NST + n];
    sC[i] = Csp[((size_t)kb*LN + loc)*NST + n];
  }
  float A[NST];
  const float* ap = A_logs + ((size_t)k*DIN + d)*NST;
  #pragma unroll
  for (int n=0;n<NST;n++) A[n] = -__expf(ap[n]);
  float h[NST];
  size_t hb = (((size_t)kb*NC + c)*DIN + d)*NST;
  #pragma unroll
  for (int n=0;n<NST;n++) h[n] = hin[hb+n];
  __syncthreads();
  const float* dp = delta + (size_t)kb*LN*DIN + d;
  const float* up = xc + (size_t)b*LN*DIN + d;
  float* yp = ysum + (size_t)b*LN*DIN + d;
  for (int sl = 0; sl < CL; sl++){
    int loc = seq_to_loc(k, c*CL + sl);
    float dl = dp[(size_t)loc*DIN];
    float uu = up[(size_t)loc*DIN];
    float du = dl * uu;
    const float* bb = sB + sl*NST;
    const float* cc2 = sC + sl*NST;
    float y = 0.f;
    #pragma unroll
    for (int n=0;n<NST;n++){
      float e = __expf(dl * A[n]);
      h[n] = e*h[n] + du*bb[n];
      y += h[n]*cc2[n];
    }
    atomicAdd(&yp[(size_t)loc*DIN], y);
  }
}

// ---------------- K7: LayerNorm + gate(silu z) + out_proj (96x192) ----------------
// ow staged in LDS (coalesced once per block); pad 193 => read sow[cc*193+i] is a
// 2-way bank alias (free), sg read is broadcast. Same math as before.
__global__ __launch_bounds__(256) void k7_out(const float* __restrict__ ysum,
    const float* __restrict__ sz, const float* __restrict__ gamma,
    const float* __restrict__ beta, const float* __restrict__ ow,
    float* __restrict__ out){
  __shared__ float sg[8*192];
  __shared__ float sow[96*193];
  int t = threadIdx.x;
  // stage ow coalesced (96x192)
  for (int f = t; f < DMODEL*DIN; f += 256){
    int row = f / DIN, col = f % DIN;
    sow[row*193 + col] = ow[f];
  }
  int m0 = blockIdx.x * 8;
  int li = t >> 5;
  int j  = t & 31;
  int m = m0 + li;
  const float* yr = ysum + (size_t)m*DIN;
  float vals[6];
  float s1 = 0.f, s2 = 0.f;
  #pragma unroll
  for (int q=0;q<6;q++){
    float v = yr[j + 32*q];
    vals[q] = v; s1 += v; s2 += v*v;
  }
  #pragma unroll
  for (int off=16; off>=1; off>>=1){
    s1 += __shfl_xor(s1, off);
    s2 += __shfl_xor(s2, off);
  }
  float mu  = s1 * (1.0f/192.0f);
  float var = s2 * (1.0f/192.0f) - mu*mu;
  float rstd = rsqrtf(var + 1e-5f);
  const float* zr = sz + (size_t)m*DIN;
  #pragma unroll
  for (int q=0;q<6;q++){
    int dd = j + 32*q;
    float v = (vals[q]-mu)*rstd*gamma[dd] + beta[dd];
    sg[li*192 + dd] = v * zr[dd];
  }
  __syncthreads();
  for (int o = t; o < 8*DMODEL; o += 256){
    int lo = o / DMODEL; int cc = o % DMODEL;
    const float* gr = sg + lo*192;
    const float* wr = sow + cc*193;
    float a = 0.f;
    #pragma unroll 8
    for (int i=0;i<192;i++){
      a += gr[i]*wr[i];
    }
    out[(size_t)(m0+lo)*DMODEL + cc] = a;
  }
}

extern "C" void kernel_launch(void* const* d_in, const int* in_sizes, int n_in,
                              void* d_out, int out_size, void* d_ws, size_t ws_size,
                              hipStream_t stream){
  (void)in_sizes; (void)n_in; (void)out_size; (void)ws_size;
  const float* x    = (const float*)d_in[0];
  const float* ipw  = (const float*)d_in[1];
  const float* cw   = (const float*)d_in[2];
  const float* cb   = (const float*)d_in[3];
  const float* xpw  = (const float*)d_in[4];
  const float* dtw  = (const float*)d_in[5];
  const float* dtb  = (const float*)d_in[6];
  const float* alog = (const float*)d_in[7];
  const float* Ds   = (const float*)d_in[8];
  const float* gam  = (const float*)d_in[9];
  const float* bet  = (const float*)d_in[10];
  const float* ow   = (const float*)d_in[11];
  float* out = (float*)d_out;

  float* ws = (float*)d_ws;
  const size_t BLD  = (size_t)BN*LN*DIN;          // 2,408,448
  const size_t KBLN = (size_t)KD*BN*LN*NST;       //   802,816
  const size_t SUMN = (size_t)KD*BN*NC*DIN*NST;   // 2,752,512

  float* xc    = ws;
  float* sz    = ws + BLD;
  float* ysum  = ws + 2*BLD;
  float* delta = ws + 3*BLD;        // 4*BLD
  float* xi    = delta;             // alias: xi dead once K2 done, K3 overwrites with delta
  float* Bsp   = ws + 7*BLD;
  float* Csp   = Bsp + KBLN;
  float* Pc    = Csp + KBLN;        // pass2 overwrites Pc with h_in (per-thread read-then-write)
  float* Hc    = Pc + SUMN;

  k1_inproj<<<dim3(392,4), 256, 0, stream>>>(x, ipw, xi, sz);
  k2_conv<<<2352, 256, 0, stream>>>(xi, cw, cb, Ds, xc, ysum);
  k3_proj<<<dim3(49,4,4), 256, 0, stream>>>(xc, xpw, dtw, dtb, delta, Bsp, Csp);
  k4_pass1<<<dim3(NC,4,4), 192, 0, stream>>>(delta, xc, Bsp, alog, Pc, Hc);
  k5_pass2<<<192, 256, 0, stream>>>(Pc, Hc);
  k6_pass3<<<dim3(NC,4,4), 192, 0, stream>>>(delta, xc, Bsp, Csp, alog, Pc, ysum);
  k7_out<<<1568, 256, 0, stream>>>(ysum, sz, gam, bet, ow, out);
}

// Round 10
// 366.230 us; speedup vs baseline: 1.4804x; 1.1767x over previous
//
#include <hip/hip_runtime.h>
#include <math.h>

#define HN 56
#define WN 56
#define LN 3136
#define BN 4
#define DIN 192
#define NST 16
#define KD 4
#define DTR 6
#define CPROJ 38
#define CL 56
#define NC 56
#define DMODEL 96

__device__ __forceinline__ float silu_f(float x){ return x / (1.0f + __expf(-x)); }
__device__ __forceinline__ float softplus_f(float x){ return (x > 20.0f) ? x : log1pf(__expf(x)); }

// sequence position s of direction k -> row-major spatial location
__device__ __forceinline__ int seq_to_loc(int k, int s){
  int ss = (k & 2) ? (LN - 1 - s) : s;
  if (k & 1) { int h = ss % HN; int w = ss / HN; return h * WN + w; }
  return ss;
}

// ---------------- K1: in_proj GEMM (12544 x 384, K=96) ----------------
__global__ __launch_bounds__(256) void k1_inproj(const float* __restrict__ x,
    const float* __restrict__ w, float* __restrict__ xi, float* __restrict__ sz){
  __shared__ float sx[32*100];   // padded stride 100 to avoid bank conflicts
  __shared__ float sw[96*100];
  int t = threadIdx.x;
  int m0 = blockIdx.x * 32;          // row tile
  int g  = blockIdx.y;               // col group: cols g*96 .. g*96+95
  const float* xb = x + (size_t)m0 * 96;
  const float* wb = w + (size_t)g * 96 * 96;
  for (int i = t; i < 32*96; i += 256) sx[(i/96)*100 + (i%96)] = xb[i];
  for (int i = t; i < 96*96; i += 256) sw[(i/96)*100 + (i%96)] = wb[i];
  __syncthreads();
  int li0 = (t & 7) * 4;
  int c0  = (t >> 3) * 3;
  float acc[4][3];
  #pragma unroll
  for (int j=0;j<4;j++){ acc[j][0]=0.f; acc[j][1]=0.f; acc[j][2]=0.f; }
  for (int i = 0; i < 96; i += 4) {
    float4 xv[4], wv[3];
    #pragma unroll
    for (int j=0;j<4;j++) xv[j] = *(const float4*)&sx[(li0+j)*100 + i];
    #pragma unroll
    for (int m=0;m<3;m++) wv[m] = *(const float4*)&sw[(c0+m)*100 + i];
    #pragma unroll
    for (int j=0;j<4;j++){
      #pragma unroll
      for (int m=0;m<3;m++){
        acc[j][m] += xv[j].x*wv[m].x + xv[j].y*wv[m].y + xv[j].z*wv[m].z + xv[j].w*wv[m].w;
      }
    }
  }
  #pragma unroll
  for (int j=0;j<4;j++){
    int row = m0 + li0 + j;
    #pragma unroll
    for (int m=0;m<3;m++){
      int o = g*96 + c0 + m;
      float v = acc[j][m];
      if (o < DIN) xi[(size_t)row*DIN + o] = v;
      else         sz[(size_t)row*DIN + (o - DIN)] = silu_f(v);
    }
  }
}

// ---------------- K2: depthwise conv 3x3 + silu; also y_init = xc * sum_k D ----------------
__global__ __launch_bounds__(256) void k2_conv(const float* __restrict__ xi,
    const float* __restrict__ cw, const float* __restrict__ cb,
    const float* __restrict__ Ds,
    float* __restrict__ xc, float* __restrict__ ysum){
  int t = blockIdx.x * 256 + threadIdx.x;
  const int total = BN * LN * (DIN/4);
  if (t >= total) return;
  int c4 = t % (DIN/4); int m = t / (DIN/4);
  int c = c4 * 4;
  int b = m / LN; int loc = m % LN;
  int h = loc / WN; int w = loc % WN;
  float acc[4];
  #pragma unroll
  for (int j=0;j<4;j++) acc[j] = cb[c+j];
  float wgt[4][9];
  #pragma unroll
  for (int j=0;j<4;j++)
    #pragma unroll
    for (int q=0;q<9;q++) wgt[j][q] = cw[(c+j)*9 + q];
  for (int dh=-1; dh<=1; dh++){
    int hh = h + dh; if (hh < 0 || hh >= HN) continue;
    for (int dw=-1; dw<=1; dw++){
      int ww = w + dw; if (ww < 0 || ww >= WN) continue;
      const float4 xv = *(const float4*)&xi[((size_t)(b*LN + hh*WN + ww))*DIN + c];
      int q = (dh+1)*3 + (dw+1);
      acc[0] += xv.x * wgt[0][q];
      acc[1] += xv.y * wgt[1][q];
      acc[2] += xv.z * wgt[2][q];
      acc[3] += xv.w * wgt[3][q];
    }
  }
  float4 xcv, yv;
  #pragma unroll
  for (int j=0;j<4;j++){
    float v = silu_f(acc[j]);
    float sd = Ds[c+j] + Ds[DIN + c+j] + Ds[2*DIN + c+j] + Ds[3*DIN + c+j];
    ((float*)&xcv)[j] = v;
    ((float*)&yv)[j]  = v * sd;
  }
  *(float4*)&xc[(size_t)m*DIN + c]   = xcv;
  *(float4*)&ysum[(size_t)m*DIN + c] = yv;
}

// ---------------- K3 v3: x_proj (38x192) + dt_proj + softplus ----------------
// No X staging (global float4 stream, L2-resident, 8-way lane merge) -> no main-loop
// barriers, LDS 37.1KB -> 4 blocks/CU. W in LDS stride 196 (conflict-free, verified
// R9: conflicts 3.96M->163K). sdt transposed [r][d] to kill stride-6 conflict.
__global__ __launch_bounds__(256) void k3_proj(const float* __restrict__ xc,
    const float* __restrict__ xpw,   // (4,38,192)
    const float* __restrict__ dtw,   // (4,192,6)
    const float* __restrict__ dtb,   // (4,192)
    float* __restrict__ delta, float* __restrict__ Bsp, float* __restrict__ Csp){
  __shared__ float sw[40*196];   // 38 real rows + 2 zero rows, padded stride
  __shared__ float sdt[DTR*DIN]; // transposed dt_projs_weight
  __shared__ float sp[64*8];
  int t = threadIdx.x;
  int loc0 = blockIdx.x * 64;
  int b = blockIdx.y;
  int k = blockIdx.z;
  int kb = k*BN + b;
  const float* wk = xpw + (size_t)k*CPROJ*DIN;
  // stage W (40x48 float4s), coalesced
  for (int f = t; f < 40*48; f += 256){
    int row = f / 48, cf = f % 48;
    float4 v;
    if (row < CPROJ) v = *(const float4*)&wk[(size_t)row*DIN + cf*4];
    else             v = make_float4(0.f,0.f,0.f,0.f);
    *(float4*)&sw[row*196 + cf*4] = v;
  }
  // stage dtw transposed: sdt[r][d] = dtw[d][r] (coalesced read)
  const float* dtwk = dtw + (size_t)k*DIN*DTR;
  for (int f = t; f < DIN*DTR; f += 256){
    int d = f / DTR, r = f % DTR;
    sdt[r*DIN + d] = dtwk[f];
  }
  int rowg = t >> 3;   // 0..31
  int colg = t & 7;    // 0..7
  float acc[2][5];
  #pragma unroll
  for (int r=0;r<2;r++)
    #pragma unroll
    for (int c=0;c<5;c++) acc[r][c] = 0.f;
  const float* xr0 = xc + ((size_t)b*LN + loc0 + rowg*2)*DIN;
  const float* xr1 = xr0 + DIN;
  __syncthreads();
  #pragma unroll 4
  for (int i = 0; i < 48; i++){
    float4 xv0 = *(const float4*)&xr0[i*4];
    float4 xv1 = *(const float4*)&xr1[i*4];
    #pragma unroll
    for (int c=0;c<5;c++){
      float4 wv = *(const float4*)&sw[(colg*5+c)*196 + i*4];
      acc[0][c] += xv0.x*wv.x + xv0.y*wv.y + xv0.z*wv.z + xv0.w*wv.w;
      acc[1][c] += xv1.x*wv.x + xv1.y*wv.y + xv1.z*wv.z + xv1.w*wv.w;
    }
  }
  // scatter results: cols 0..5 -> sp (LDS), 6..21 -> B, 22..37 -> C
  size_t kbL = (size_t)kb*LN;
  #pragma unroll
  for (int r=0;r<2;r++){
    int lrow = rowg*2 + r;
    int loc  = loc0 + lrow;
    #pragma unroll
    for (int c=0;c<5;c++){
      int col = colg*5 + c;
      float v = acc[r][c];
      if (col < DTR)               sp[lrow*8 + col] = v;
      else if (col < DTR+NST)      Bsp[(kbL+loc)*NST + (col-DTR)] = v;
      else if (col < CPROJ)        Csp[(kbL+loc)*NST + (col-DTR-NST)] = v;
    }
  }
  __syncthreads();
  // epilogue: delta = softplus(dtb + sp . dtw^T)
  const float* dtbk = dtb + (size_t)k*DIN;
  for (int o = t; o < 64*DIN; o += 256){
    int li = o / DIN, d = o % DIN;
    float a = dtbk[d];
    const float* pr = &sp[li*8];
    #pragma unroll
    for (int r=0;r<DTR;r++) a += pr[r]*sdt[r*DIN + d];
    delta[(kbL + loc0 + li)*DIN + d] = softplus_f(a);
  }
}

// ---------------- K4: scan pass 1 — per-chunk summaries (P = prod dA, Hc = local end state) ----------------
__global__ __launch_bounds__(192) void k4_pass1(const float* __restrict__ delta,
    const float* __restrict__ xc, const float* __restrict__ Bsp,
    const float* __restrict__ A_logs,
    float* __restrict__ Pc, float* __restrict__ Hc){
  __shared__ float sB[CL*NST];
  int d = threadIdx.x;
  int c = blockIdx.x, b = blockIdx.y, k = blockIdx.z;
  int kb = k*BN + b;
  for (int i = d; i < CL*NST; i += 192){
    int sl = i / NST, n = i % NST;
    int loc = seq_to_loc(k, c*CL + sl);
    sB[i] = Bsp[((size_t)kb*LN + loc)*NST + n];
  }
  float A[NST];
  const float* ap = A_logs + ((size_t)k*DIN + d)*NST;
  #pragma unroll
  for (int n=0;n<NST;n++) A[n] = -__expf(ap[n]);
  __syncthreads();
  float h[NST], P[NST];
  #pragma unroll
  for (int n=0;n<NST;n++){ h[n]=0.f; P[n]=1.f; }
  const float* dp = delta + (size_t)kb*LN*DIN + d;
  const float* up = xc + (size_t)b*LN*DIN + d;
  for (int sl = 0; sl < CL; sl++){
    int loc = seq_to_loc(k, c*CL + sl);
    float dl = dp[(size_t)loc*DIN];
    float uu = up[(size_t)loc*DIN];
    float du = dl * uu;
    const float* bb = sB + sl*NST;
    #pragma unroll
    for (int n=0;n<NST;n++){
      float e = __expf(dl * A[n]);
      h[n] = e*h[n] + du*bb[n];
      P[n] *= e;
    }
  }
  size_t base = (((size_t)kb*NC + c)*DIN + d)*NST;
  #pragma unroll
  for (int n=0;n<NST;n++){ Pc[base+n] = P[n]; Hc[base+n] = h[n]; }
}

// ---------------- K5: scan pass 2 — compose chunk summaries; writes h_in over Pc (alias) ----------------
__global__ __launch_bounds__(256) void k5_pass2(float* __restrict__ Pc,
    const float* __restrict__ Hc){
  int idx = blockIdx.x*256 + threadIdx.x;
  if (idx >= KD*BN*DIN*NST) return;
  int kb = idx / (DIN*NST);
  int dn = idx % (DIN*NST);
  size_t base = (size_t)kb*NC*DIN*NST + dn;
  float h = 0.f;
  for (int c = 0; c < NC; c++){
    size_t o = base + (size_t)c*DIN*NST;
    float p = Pc[o];
    float hv = Hc[o];
    Pc[o] = h;          // store h_in for chunk c
    h = p*h + hv;
  }
}

// ---------------- K6: scan pass 3 — recompute with correct h_in, emit y ----------------
__global__ __launch_bounds__(192) void k6_pass3(const float* __restrict__ delta,
    const float* __restrict__ xc, const float* __restrict__ Bsp,
    const float* __restrict__ Csp, const float* __restrict__ A_logs,
    const float* __restrict__ hin, float* __restrict__ ysum){
  __shared__ float sB[CL*NST];
  __shared__ float sC[CL*NST];
  int d = threadIdx.x;
  int c = blockIdx.x, b = blockIdx.y, k = blockIdx.z;
  int kb = k*BN + b;
  for (int i = d; i < CL*NST; i += 192){
    int sl = i / NST, n = i % NST;
    int loc = seq_to_loc(k, c*CL + sl);
    sB[i] = Bsp[((size_t)kb*LN + loc)*NST + n];
    sC[i] = Csp[((size_t)kb*LN + loc)*NST + n];
  }
  float A[NST];
  const float* ap = A_logs + ((size_t)k*DIN + d)*NST;
  #pragma unroll
  for (int n=0;n<NST;n++) A[n] = -__expf(ap[n]);
  float h[NST];
  size_t hb = (((size_t)kb*NC + c)*DIN + d)*NST;
  #pragma unroll
  for (int n=0;n<NST;n++) h[n] = hin[hb+n];
  __syncthreads();
  const float* dp = delta + (size_t)kb*LN*DIN + d;
  const float* up = xc + (size_t)b*LN*DIN + d;
  float* yp = ysum + (size_t)b*LN*DIN + d;
  for (int sl = 0; sl < CL; sl++){
    int loc = seq_to_loc(k, c*CL + sl);
    float dl = dp[(size_t)loc*DIN];
    float uu = up[(size_t)loc*DIN];
    float du = dl * uu;
    const float* bb = sB + sl*NST;
    const float* cc2 = sC + sl*NST;
    float y = 0.f;
    #pragma unroll
    for (int n=0;n<NST;n++){
      float e = __expf(dl * A[n]);
      h[n] = e*h[n] + du*bb[n];
      y += h[n]*cc2[n];
    }
    atomicAdd(&yp[(size_t)loc*DIN], y);
  }
}

// ---------------- K7: LayerNorm + gate(silu z) + out_proj (96x192) ----------------
// ow staged in LDS (coalesced once per block); pad 193 => read sow[cc*193+i] is a
// 2-way bank alias (free), sg read is broadcast. Same math as before.
__global__ __launch_bounds__(256) void k7_out(const float* __restrict__ ysum,
    const float* __restrict__ sz, const float* __restrict__ gamma,
    const float* __restrict__ beta, const float* __restrict__ ow,
    float* __restrict__ out){
  __shared__ float sg[8*192];
  __shared__ float sow[96*193];
  int t = threadIdx.x;
  // stage ow coalesced (96x192)
  for (int f = t; f < DMODEL*DIN; f += 256){
    int row = f / DIN, col = f % DIN;
    sow[row*193 + col] = ow[f];
  }
  int m0 = blockIdx.x * 8;
  int li = t >> 5;
  int j  = t & 31;
  int m = m0 + li;
  const float* yr = ysum + (size_t)m*DIN;
  float vals[6];
  float s1 = 0.f, s2 = 0.f;
  #pragma unroll
  for (int q=0;q<6;q++){
    float v = yr[j + 32*q];
    vals[q] = v; s1 += v; s2 += v*v;
  }
  #pragma unroll
  for (int off=16; off>=1; off>>=1){
    s1 += __shfl_xor(s1, off);
    s2 += __shfl_xor(s2, off);
  }
  float mu  = s1 * (1.0f/192.0f);
  float var = s2 * (1.0f/192.0f) - mu*mu;
  float rstd = rsqrtf(var + 1e-5f);
  const float* zr = sz + (size_t)m*DIN;
  #pragma unroll
  for (int q=0;q<6;q++){
    int dd = j + 32*q;
    float v = (vals[q]-mu)*rstd*gamma[dd] + beta[dd];
    sg[li*192 + dd] = v * zr[dd];
  }
  __syncthreads();
  for (int o = t; o < 8*DMODEL; o += 256){
    int lo = o / DMODEL; int cc = o % DMODEL;
    const float* gr = sg + lo*192;
    const float* wr = sow + cc*193;
    float a = 0.f;
    #pragma unroll 8
    for (int i=0;i<192;i++){
      a += gr[i]*wr[i];
    }
    out[(size_t)(m0+lo)*DMODEL + cc] = a;
  }
}

extern "C" void kernel_launch(void* const* d_in, const int* in_sizes, int n_in,
                              void* d_out, int out_size, void* d_ws, size_t ws_size,
                              hipStream_t stream){
  (void)in_sizes; (void)n_in; (void)out_size; (void)ws_size;
  const float* x    = (const float*)d_in[0];
  const float* ipw  = (const float*)d_in[1];
  const float* cw   = (const float*)d_in[2];
  const float* cb   = (const float*)d_in[3];
  const float* xpw  = (const float*)d_in[4];
  const float* dtw  = (const float*)d_in[5];
  const float* dtb  = (const float*)d_in[6];
  const float* alog = (const float*)d_in[7];
  const float* Ds   = (const float*)d_in[8];
  const float* gam  = (const float*)d_in[9];
  const float* bet  = (const float*)d_in[10];
  const float* ow   = (const float*)d_in[11];
  float* out = (float*)d_out;

  float* ws = (float*)d_ws;
  const size_t BLD  = (size_t)BN*LN*DIN;          // 2,408,448
  const size_t KBLN = (size_t)KD*BN*LN*NST;       //   802,816
  const size_t SUMN = (size_t)KD*BN*NC*DIN*NST;   // 2,752,512

  float* xc    = ws;
  float* sz    = ws + BLD;
  float* ysum  = ws + 2*BLD;
  float* delta = ws + 3*BLD;        // 4*BLD
  float* xi    = delta;             // alias: xi dead once K2 done, K3 overwrites with delta
  float* Bsp   = ws + 7*BLD;
  float* Csp   = Bsp + KBLN;
  float* Pc    = Csp + KBLN;        // pass2 overwrites Pc with h_in (per-thread read-then-write)
  float* Hc    = Pc + SUMN;

  k1_inproj<<<dim3(392,4), 256, 0, stream>>>(x, ipw, xi, sz);
  k2_conv<<<2352, 256, 0, stream>>>(xi, cw, cb, Ds, xc, ysum);
  k3_proj<<<dim3(49,4,4), 256, 0, stream>>>(xc, xpw, dtw, dtb, delta, Bsp, Csp);
  k4_pass1<<<dim3(NC,4,4), 192, 0, stream>>>(delta, xc, Bsp, alog, Pc, Hc);
  k5_pass2<<<192, 256, 0, stream>>>(Pc, Hc);
  k6_pass3<<<dim3(NC,4,4), 192, 0, stream>>>(delta, xc, Bsp, Csp, alog, Pc, ysum);
  k7_out<<<1568, 256, 0, stream>>>(ysum, sz, gam, bet, ow, out);
}